// Round 10
// baseline (395.585 us; speedup 1.0000x reference)
//
#include <hip/hip_runtime.h>

#define BN_EPS 1e-5f

typedef __attribute__((ext_vector_type(8))) short bf16x8;
typedef __attribute__((ext_vector_type(4))) float f32x4;

#define ABLK 8192

// ---- sort pass A0: bucket counts via LDS histogram (dst>>8), one global
// atomicAdd per (block,bucket) instead of per edge. ----
__global__ __launch_bounds__(1024) void k_countA(const int* __restrict__ dst,
                                                 int* __restrict__ gcnt, int E, int N) {
    __shared__ int hist[1024];
    int tid = threadIdx.x;
    int NB = (N + 255) >> 8;
    int e0 = blockIdx.x * ABLK;
    int e1 = e0 + ABLK; if (e1 > E) e1 = E;
    for (int i = tid; i < NB; i += 1024) hist[i] = 0;
    __syncthreads();
    for (int e = e0 + tid; e < e1; e += 1024) atomicAdd(&hist[dst[e] >> 8], 1);
    __syncthreads();
    for (int b = tid; b < NB; b += 1024) {
        int hc = hist[b];
        if (hc) atomicAdd(&gcnt[b], hc);
    }
}

// ---- sort pass A1: exclusive scan of bucket counts -> bucket bases + cursors --
__global__ __launch_bounds__(1024) void k_scanbuckets(const int* __restrict__ gcnt,
                                                      int* __restrict__ gbase,
                                                      int* __restrict__ gcur,
                                                      int* __restrict__ rowptr,
                                                      int E, int N) {
    __shared__ int t[1024];
    int tid = threadIdx.x;
    int NB = (N + 255) >> 8;
    int v = (tid < NB) ? gcnt[tid] : 0;
    t[tid] = v;
    __syncthreads();
    for (int d = 1; d < 1024; d <<= 1) {
        int u = (tid >= d) ? t[tid - d] : 0;
        __syncthreads();
        t[tid] += u;
        __syncthreads();
    }
    int ex = t[tid] - v;  // exclusive
    if (tid < NB) { gbase[tid] = ex; gcur[tid] = ex; }
    if (tid == 0) { gbase[NB] = E; rowptr[N] = E; }
}

// ------- sort pass A: partition edges into 256-node buckets (requires N < 2^24) -
// Payload: [attr:32 | dst&255:8 | src:24]
__global__ __launch_bounds__(1024) void k_binA(const int* __restrict__ src,
                                               const int* __restrict__ dst,
                                               const float* __restrict__ attr,
                                               int* __restrict__ gcur,
                                               unsigned long long* __restrict__ tmp,
                                               int E, int N) {
    __shared__ int hist[1024];
    __shared__ int lcur[1024];
    int tid = threadIdx.x;
    int NB = (N + 255) >> 8;  // <= 1024 for N <= 262144
    int e0 = blockIdx.x * ABLK;
    int e1 = e0 + ABLK; if (e1 > E) e1 = E;
    for (int i = tid; i < NB; i += 1024) hist[i] = 0;
    __syncthreads();
    for (int e = e0 + tid; e < e1; e += 1024) atomicAdd(&hist[dst[e] >> 8], 1);
    __syncthreads();
    for (int b = tid; b < NB; b += 1024) {
        int hc = hist[b];
        lcur[b] = hc ? atomicAdd(&gcur[b], hc) : 0;
    }
    __syncthreads();
    for (int e = e0 + tid; e < e1; e += 1024) {
        int d = dst[e];
        int pos = atomicAdd(&lcur[d >> 8], 1);
        unsigned long long p = ((unsigned long long)__float_as_uint(attr[e]) << 32) |
                               ((unsigned long long)(d & 255) << 24) |
                               (unsigned int)src[e];
        tmp[pos] = p;
    }
}

// ------- sort pass B: per bucket, LDS histogram of dst&255 -> rowptr (no global
// atomics for degree counting), then exact placement via LDS cursors.
// Final edata word: [attr_fp32:32 | src:24] (plain src index; consumers shift).
__global__ __launch_bounds__(256) void k_binB3(const int* __restrict__ gbase,
                                               const unsigned long long* __restrict__ tmp,
                                               unsigned long long* __restrict__ edata,
                                               int* __restrict__ rowptr, int N) {
    __shared__ int cnt[256];
    __shared__ int scn[256];
    __shared__ int cur[256];
    int b = blockIdx.x;
    int tid = threadIdx.x;
    int nb0 = b << 8;
    int beg = gbase[b], end = gbase[b + 1];
    cnt[tid] = 0;
    __syncthreads();
    for (int e = beg + tid; e < end; e += 256)
        atomicAdd(&cnt[(int)((tmp[e] >> 24) & 255)], 1);
    __syncthreads();
    int v = cnt[tid];
    scn[tid] = v;
    __syncthreads();
    for (int d = 1; d < 256; d <<= 1) {
        int u = (tid >= d) ? scn[tid - d] : 0;
        __syncthreads();
        scn[tid] += u;
        __syncthreads();
    }
    int ex = beg + scn[tid] - v;  // exclusive within bucket + base
    int node = nb0 + tid;
    if (node < N) rowptr[node] = ex;
    cur[tid] = ex;
    __syncthreads();
    for (int e = beg + tid; e < end; e += 256) {
        unsigned long long p = tmp[e];
        int dl = (int)((p >> 24) & 255);
        int pos = atomicAdd(&cur[dl], 1);
        edata[pos] = (p & 0xFFFFFFFF00000000ull) | (p & 0xFFFFFFull);
    }
}

// ---- inline BN scale/shift from raw stats ----
__device__ __forceinline__ void bn_coeff(const float* bs, const float* gam,
                                         const float* bet, int c, float inv_n,
                                         float& sc, float& sh) {
    float mean = bs[c] * inv_n;
    float var = bs[64 + c] * inv_n - mean * mean;
    sc = gam[c] * rsqrtf(fmaxf(var, 0.f) + BN_EPS);
    sh = bet[c] - mean * sc;
}

__device__ __forceinline__ float h16lo(unsigned u) {
    return (float)__builtin_bit_cast(_Float16, (unsigned short)(u & 0xFFFFu));
}
__device__ __forceinline__ float h16hi(unsigned u) {
    return (float)__builtin_bit_cast(_Float16, (unsigned short)(u >> 16));
}

// ---- layer-0 gather on raw x (N x 4): one WAVE per node, 16 edge slots x 4 ch.
// Coalesced edata reads; shfl-reduce over edge slots. ----
__global__ __launch_bounds__(256) void k_gather4(const int* __restrict__ rowptr,
                                                 const unsigned long long* __restrict__ edata,
                                                 const float* __restrict__ x,
                                                 float* __restrict__ g4,
                                                 float* __restrict__ degw, int N) {
    int wid = (blockIdx.x * blockDim.x + threadIdx.x) >> 6;  // one wave per node
    if (wid >= N) return;
    int lane = threadIdx.x & 63;
    int es = lane >> 2;   // edge slot 0..15
    int ch = lane & 3;
    int beg = rowptr[wid], end = rowptr[wid + 1];
    int len = end - beg;
    float acc = 0.f, wsum = 0.f;
    for (int base = 0; base < len; base += 16) {
        int idx = base + es;
        unsigned long long p = edata[beg + (idx < len ? idx : (len ? len - 1 : 0))];
        float w = (idx < len) ? __uint_as_float((unsigned)(p >> 32)) : 0.f;
        unsigned srcb = (unsigned)p;  // src (bits 24-31 are zero)
        float v = x[(size_t)srcb * 4 + ch];
        acc = fmaf(w, v, acc);
        wsum += w;
    }
    acc += __shfl_xor(acc, 4);  wsum += __shfl_xor(wsum, 4);
    acc += __shfl_xor(acc, 8);  wsum += __shfl_xor(wsum, 8);
    acc += __shfl_xor(acc, 16); wsum += __shfl_xor(wsum, 16);
    acc += __shfl_xor(acc, 32); wsum += __shfl_xor(wsum, 32);
    if (es == 0) {
        g4[(size_t)wid * 4 + ch] = acc;
        if (ch == 0) degw[wid] = wsum;
    }
}

// ---- activation materialization: a16 = fp16(relu(BN(h))), linear [N][64] ----
__global__ __launch_bounds__(256) void k_act(const float* __restrict__ h,
                                             const float* __restrict__ bs,
                                             const float* __restrict__ gam,
                                             const float* __restrict__ bet,
                                             unsigned short* __restrict__ a16,
                                             int N) {
    __shared__ float scS[64], shS[64];
    int tid = threadIdx.x;
    if (tid < 64) {
        float sc, sh;
        bn_coeff(bs, gam, bet, tid, 1.f / (float)N, sc, sh);
        scS[tid] = sc; shS[tid] = sh;
    }
    __syncthreads();
    int c0 = (tid & 15) << 2;
    float4 scv = *(const float4*)&scS[c0];
    float4 shv = *(const float4*)&shS[c0];
    int total = N << 4;  // N*64/4 chunks
    for (int t = blockIdx.x * 256 + tid; t < total; t += gridDim.x * 256) {
        float4 v = *(const float4*)&h[(size_t)t * 4];
        float r0 = fmaxf(fmaf(v.x, scv.x, shv.x), 0.f);
        float r1 = fmaxf(fmaf(v.y, scv.y, shv.y), 0.f);
        float r2 = fmaxf(fmaf(v.z, scv.z, shv.z), 0.f);
        float r3 = fmaxf(fmaf(v.w, scv.w, shv.w), 0.f);
        unsigned q0 = __builtin_bit_cast(unsigned short, (_Float16)r0);
        unsigned q1 = __builtin_bit_cast(unsigned short, (_Float16)r1);
        unsigned q2 = __builtin_bit_cast(unsigned short, (_Float16)r2);
        unsigned q3 = __builtin_bit_cast(unsigned short, (_Float16)r3);
        uint2 o; o.x = q0 | (q1 << 16); o.y = q2 | (q3 << 16);
        *(uint2*)&a16[(size_t)t * 4] = o;
    }
}

// ------- pull gather from pre-activated fp16: S[n] = sum_e w_e * a16[src_e] ----
// One wave per node, organized as 4 edge-streams x 16 channel-quads. Each lane
// loads uint2 (8B = 4 fp16); a stream's 16 lanes cover the full 128B row. Per
// 16 edges: 1 edata load + 1 row load + 4x(extract/addr/4cvt/4fma) wave-instrs
// (~3.25 instr/edge vs 4 before). 4 float4 acc chains -> ~16 outstanding row
// reads per wave. Streams combined via shfl_xor(16/32); lanes 0-15 store f4.
__global__ __launch_bounds__(256) void k_gather16(const int* __restrict__ rowptr,
                                                  const unsigned long long* __restrict__ edata,
                                                  const unsigned short* __restrict__ a16,
                                                  float* __restrict__ S, int N) {
    int wid = (blockIdx.x * blockDim.x + threadIdx.x) >> 6;  // one wave per node
    if (wid >= N) return;
    int lane = threadIdx.x & 63;
    int s = lane >> 4;           // edge stream 0..3
    int q = lane & 15;           // channel quad (channels 4q..4q+3)
    unsigned c8 = (unsigned)(q << 3);  // byte offset of the quad in a 128B row

    int beg = rowptr[wid], end = rowptr[wid + 1];
    int len = end - beg;
    float4 acc[4];
#pragma unroll
    for (int j = 0; j < 4; ++j) { acc[j].x = 0.f; acc[j].y = 0.f; acc[j].z = 0.f; acc[j].w = 0.f; }
    int nFull = len & ~15;
    for (int base = 0; base < nFull; base += 16) {
#pragma unroll
        for (int j = 0; j < 4; ++j) {
            unsigned long long p = edata[beg + base + 4 * j + s];
            float w = __uint_as_float((unsigned)(p >> 32));
            unsigned off = (((unsigned)p) << 7) | c8;
            uint2 v = *(const uint2*)((const char*)a16 + off);
            acc[j].x = fmaf(w, h16lo(v.x), acc[j].x);
            acc[j].y = fmaf(w, h16hi(v.x), acc[j].y);
            acc[j].z = fmaf(w, h16lo(v.y), acc[j].z);
            acc[j].w = fmaf(w, h16hi(v.y), acc[j].w);
        }
    }
    if (nFull < len) {
#pragma unroll
        for (int j = 0; j < 4; ++j) {
            int idx = nFull + 4 * j + s;
            unsigned long long p = edata[beg + (idx < len ? idx : (len ? len - 1 : 0))];
            float w = (idx < len) ? __uint_as_float((unsigned)(p >> 32)) : 0.f;
            unsigned off = (((unsigned)p) << 7) | c8;
            uint2 v = *(const uint2*)((const char*)a16 + off);
            acc[j].x = fmaf(w, h16lo(v.x), acc[j].x);
            acc[j].y = fmaf(w, h16hi(v.x), acc[j].y);
            acc[j].z = fmaf(w, h16lo(v.y), acc[j].z);
            acc[j].w = fmaf(w, h16hi(v.y), acc[j].w);
        }
    }
    float4 r;
    r.x = (acc[0].x + acc[1].x) + (acc[2].x + acc[3].x);
    r.y = (acc[0].y + acc[1].y) + (acc[2].y + acc[3].y);
    r.z = (acc[0].z + acc[1].z) + (acc[2].z + acc[3].z);
    r.w = (acc[0].w + acc[1].w) + (acc[2].w + acc[3].w);
    r.x += __shfl_xor(r.x, 16); r.y += __shfl_xor(r.y, 16);
    r.z += __shfl_xor(r.z, 16); r.w += __shfl_xor(r.w, 16);
    r.x += __shfl_xor(r.x, 32); r.y += __shfl_xor(r.y, 32);
    r.z += __shfl_xor(r.z, 32); r.w += __shfl_xor(r.w, 32);
    if (s == 0) {
        *(float4*)&S[(size_t)wid * 64 + (q << 2)] = r;
    }
}

// ---- bf16x3 split helpers ----
__device__ __forceinline__ void split_pack8(const float* v, uint4& H, uint4& L) {
    unsigned hb[8], lb[8];
#pragma unroll
    for (int j = 0; j < 8; ++j) {
        unsigned b = __float_as_uint(v[j]);
        unsigned rb = (b + 0x7FFFu + ((b >> 16) & 1u)) & 0xFFFF0000u;  // RNE bf16
        hb[j] = rb >> 16;
        float lo = v[j] - __uint_as_float(rb);  // exact
        lb[j] = __float_as_uint(lo) >> 16;
    }
    H.x = hb[0] | (hb[1] << 16); H.y = hb[2] | (hb[3] << 16);
    H.z = hb[4] | (hb[5] << 16); H.w = hb[6] | (hb[7] << 16);
    L.x = lb[0] | (lb[1] << 16); L.y = lb[2] | (lb[3] << 16);
    L.z = lb[4] | (lb[5] << 16); L.w = lb[6] | (lb[7] << 16);
}

__device__ __forceinline__ void split_frag(const float* w, bf16x8& hi, bf16x8& lo) {
#pragma unroll
    for (int j = 0; j < 8; ++j) {
        unsigned b = __float_as_uint(w[j]);
        unsigned rb = (b + 0x7FFFu + ((b >> 16) & 1u)) & 0xFFFF0000u;
        hi[j] = (short)(rb >> 16);
        float lof = w[j] - __uint_as_float(rb);
        lo[j] = (short)(__float_as_uint(lof) >> 16);
    }
}

// --- h_raw_out = S@W1 + x@W3 - dw*(x@W2) + dw*b1 + b3 via bf16x3 MFMA.
// PRE=1: x_i operand read from pre-activated fp16 a16 (exact hi/lo split since
// fp16 mantissa (11b) fits in bf16hi+lo (16b)). EMB=1 (layer 0): S/x rows
// reconstructed from g4/x via Wemb during staging.
template <int PRE, int EMB>
__global__ __launch_bounds__(512) void k_update(
    const float* __restrict__ S, float* __restrict__ h,
    const float* __restrict__ degw,
    const float* __restrict__ xin, const float* __restrict__ g4,
    const float* __restrict__ Wemb, const float* __restrict__ bemb,
    const unsigned short* __restrict__ a16,
    const float* __restrict__ W1, const float* __restrict__ b1,
    const float* __restrict__ W2, const float* __restrict__ W3,
    const float* __restrict__ b3,
    float* __restrict__ bnstats, int N) {
    // [Shi | Slo | Hhi | Hlo], 4096 ushorts (8KB) each = 32KB
    __shared__ __align__(16) unsigned short sA[16384];
    __shared__ float dwS[64];

    int tid = threadIdx.x;
    int lane = tid & 63;
    int wv = tid >> 6;            // wave 0..7
    int mg = wv >> 2;             // row-group: rows mg*32 .. mg*32+31
    int nb = wv & 3;              // col-block: cols nb*16 .. nb*16+15
    int c = (nb << 4) | (lane & 15);
    int krow = (lane >> 4) << 3;  // k-offset of this lane's fragment elems

    // ---- B fragments (weights) in registers, one-time ----
    bf16x8 B1h[2], B1l[2], B2h[2], B2l[2], B3h[2], B3l[2];
#pragma unroll
    for (int ks = 0; ks < 2; ++ks) {
        float w1v[8], w2v[8], w3v[8];
        int kb = ks * 32 + krow;
#pragma unroll
        for (int j = 0; j < 8; ++j) {
            int idx = (kb + j) * 64 + c;
            w1v[j] = W1[idx];
            w2v[j] = W2[idx];
            w3v[j] = W3[idx];
        }
        split_frag(w1v, B1h[ks], B1l[ks]);
        split_frag(w2v, B2h[ks], B2l[ks]);
        split_frag(w3v, B3h[ks], B3l[ks]);
    }
    float b1c = b1[c], b3c = b3[c];

    // ---- staging role: thread handles row r, k-chunk kg (8 consecutive k) ----
    int r = tid >> 3;   // 0..63
    int kg = tid & 7;   // 0..7
    int k0 = kg << 3;
    int slot = ((((r >> 4) * 2 + (kg >> 2)) * 64) + ((kg & 3) << 4) + (r & 15)) * 8;

    float we0[8], we1[8], we2[8], we3[8], bev[8];
    if (EMB) {
#pragma unroll
        for (int j = 0; j < 8; ++j) {
            we0[j] = Wemb[k0 + j];
            we1[j] = Wemb[64 + k0 + j];
            we2[j] = Wemb[128 + k0 + j];
            we3[j] = Wemb[192 + k0 + j];
            bev[j] = bemb[k0 + j];
        }
    }

    float bsum = 0.f, bsq = 0.f;
    int numTiles = (N + 63) >> 6;
    for (int tile = blockIdx.x; tile < numTiles; tile += gridDim.x) {
        int n0 = tile << 6;
        __syncthreads();  // protect LDS from previous iteration's readers
        {
            int n = n0 + r;
            float sv[8], hv[8];
            if (n < N) {
                if (EMB) {
                    float4 g = *(const float4*)&g4[(size_t)n * 4];
                    float4 xr = *(const float4*)&xin[(size_t)n * 4];
                    float dw = degw[n];
#pragma unroll
                    for (int j = 0; j < 8; ++j) {
                        sv[j] = fmaf(g.x, we0[j], fmaf(g.y, we1[j],
                                 fmaf(g.z, we2[j], fmaf(g.w, we3[j], dw * bev[j]))));
                        hv[j] = fmaf(xr.x, we0[j], fmaf(xr.y, we1[j],
                                 fmaf(xr.z, we2[j], fmaf(xr.w, we3[j], bev[j]))));
                    }
                } else {
                    const float* Sp = &S[(size_t)n * 64 + k0];
                    float4 s0_ = *(const float4*)Sp;
                    float4 s1_ = *(const float4*)(Sp + 4);
                    sv[0]=s0_.x; sv[1]=s0_.y; sv[2]=s0_.z; sv[3]=s0_.w;
                    sv[4]=s1_.x; sv[5]=s1_.y; sv[6]=s1_.z; sv[7]=s1_.w;
                    uint4 hp = *(const uint4*)((const char*)a16 + (((size_t)n) << 7) + (k0 << 1));
                    hv[0] = h16lo(hp.x); hv[1] = h16hi(hp.x);
                    hv[2] = h16lo(hp.y); hv[3] = h16hi(hp.y);
                    hv[4] = h16lo(hp.z); hv[5] = h16hi(hp.z);
                    hv[6] = h16lo(hp.w); hv[7] = h16hi(hp.w);
                }
            } else {
#pragma unroll
                for (int j = 0; j < 8; ++j) { sv[j] = 0.f; hv[j] = 0.f; }
            }
            uint4 H, L;
            split_pack8(sv, H, L);
            *(uint4*)&sA[slot] = H;
            *(uint4*)&sA[4096 + slot] = L;
            split_pack8(hv, H, L);
            *(uint4*)&sA[8192 + slot] = H;
            *(uint4*)&sA[12288 + slot] = L;
            if (tid < 64) dwS[tid] = (n0 + tid < N) ? degw[n0 + tid] : 0.f;
        }
        __syncthreads();
        // ---- MFMA: acc over K=64 (2 K-steps), 2 M-subtiles per wave ----
        f32x4 accP[2] = {{0.f,0.f,0.f,0.f},{0.f,0.f,0.f,0.f}};
        f32x4 accN[2] = {{0.f,0.f,0.f,0.f},{0.f,0.f,0.f,0.f}};
#pragma unroll
        for (int ks = 0; ks < 2; ++ks) {
#pragma unroll
            for (int mtg = 0; mtg < 2; ++mtg) {
                int mt = mg * 2 + mtg;
                int base = ((mt * 2 + ks) * 64 + lane) * 8;
                bf16x8 aSh = *(const bf16x8*)&sA[base];
                bf16x8 aSl = *(const bf16x8*)&sA[4096 + base];
                bf16x8 aHh = *(const bf16x8*)&sA[8192 + base];
                bf16x8 aHl = *(const bf16x8*)&sA[12288 + base];
                f32x4 p = accP[mtg], q = accN[mtg];
                p = __builtin_amdgcn_mfma_f32_16x16x32_bf16(aSh, B1h[ks], p, 0, 0, 0);
                p = __builtin_amdgcn_mfma_f32_16x16x32_bf16(aSl, B1h[ks], p, 0, 0, 0);
                p = __builtin_amdgcn_mfma_f32_16x16x32_bf16(aSh, B1l[ks], p, 0, 0, 0);
                p = __builtin_amdgcn_mfma_f32_16x16x32_bf16(aHh, B3h[ks], p, 0, 0, 0);
                p = __builtin_amdgcn_mfma_f32_16x16x32_bf16(aHl, B3h[ks], p, 0, 0, 0);
                p = __builtin_amdgcn_mfma_f32_16x16x32_bf16(aHh, B3l[ks], p, 0, 0, 0);
                q = __builtin_amdgcn_mfma_f32_16x16x32_bf16(aHh, B2h[ks], q, 0, 0, 0);
                q = __builtin_amdgcn_mfma_f32_16x16x32_bf16(aHl, B2h[ks], q, 0, 0, 0);
                q = __builtin_amdgcn_mfma_f32_16x16x32_bf16(aHh, B2l[ks], q, 0, 0, 0);
                accP[mtg] = p; accN[mtg] = q;
            }
        }
        // ---- epilogue: C layout col=lane&15, row=(lane>>4)*4+j ----
#pragma unroll
        for (int mtg = 0; mtg < 2; ++mtg) {
            int rowb = mg * 32 + mtg * 16 + ((lane >> 4) << 2);
            float4 dwv = *(const float4*)&dwS[rowb];
            float dwa[4] = {dwv.x, dwv.y, dwv.z, dwv.w};
#pragma unroll
            for (int j = 0; j < 4; ++j) {
                int n = n0 + rowb + j;
                if (n < N) {
                    float val = accP[mtg][j] - dwa[j] * accN[mtg][j] + dwa[j] * b1c + b3c;
                    h[(size_t)n * 64 + c] = val;  // raw (pre-BN)
                    bsum += val;
                    bsq += val * val;
                }
            }
        }
    }
    // ---- BN stats reduction (reuse sA as 1024 floats) ----
    __syncthreads();
    float* red = (float*)sA;
    red[tid] = bsum;
    red[512 + tid] = bsq;
    __syncthreads();
    if (tid < 64) {
        int nb_ = tid >> 4, cl = tid & 15;
        float s = 0.f, qq = 0.f;
#pragma unroll
        for (int i = 0; i < 8; ++i) {
            int t = ((i & 1) << 8) + (nb_ << 6) + ((i >> 1) << 4) + cl;
            s += red[t];
            qq += red[512 + t];
        }
        atomicAdd(&bnstats[tid], s);
        atomicAdd(&bnstats[64 + tid], qq);
    }
}

// ------- pool phase 1: per-graph sums of act(h_raw), sorted-run + atomics -------
#define POOL_TILE 128
__global__ __launch_bounds__(256) void k_poolsum(const float* __restrict__ h,
                                                 const int* __restrict__ batch,
                                                 const float* __restrict__ bsp,
                                                 const float* __restrict__ gamp,
                                                 const float* __restrict__ betp,
                                                 float* __restrict__ gsums, int N) {
    int tid = threadIdx.x;
    int c = tid & 63, q = tid >> 6;
    float sc, sh_;
    bn_coeff(bsp, gamp, betp, c, 1.f / (float)N, sc, sh_);
    int n0 = blockIdx.x * POOL_TILE;
    int nEnd = n0 + POOL_TILE; if (nEnd > N) nEnd = N;
    int g = -1;
    float acc = 0.f;
    for (int n = n0 + q; n < nEnd; n += 4) {
        int b = batch[n];
        if (b != g) {
            if (g >= 0) atomicAdd(&gsums[(size_t)g * 64 + c], acc);
            g = b; acc = 0.f;
        }
        acc += fmaxf(fmaf(h[(size_t)n * 64 + c], sc, sh_), 0.f);
    }
    if (g >= 0) atomicAdd(&gsums[(size_t)g * 64 + c], acc);
}

// ------- pool phase 2: divide by count + MLP head (one 64-thread block / graph) -
__global__ void k_head(const float* __restrict__ gsums, const int* __restrict__ batch,
                       const float* __restrict__ Wl1, const float* __restrict__ bl1,
                       const float* __restrict__ Wl2, const float* __restrict__ bl2,
                       float* __restrict__ out, int N) {
    int g = blockIdx.x;
    int c = threadIdx.x;  // 64 threads
    int lo = 0, hi = N;
    while (lo < hi) { int mid = (lo + hi) >> 1; if (batch[mid] < g) lo = mid + 1; else hi = mid; }
    int start = lo;
    hi = N;
    while (lo < hi) { int mid = (lo + hi) >> 1; if (batch[mid] < g + 1) lo = mid + 1; else hi = mid; }
    int cnt = lo - start;
    float denom = (float)(cnt > 0 ? cnt : 1);
    __shared__ float gS[64], yS[64];
    gS[c] = gsums[(size_t)g * 64 + c] / denom;
    __syncthreads();
    float y = bl1[c];
    for (int k = 0; k < 64; ++k) y += gS[k] * Wl1[k * 64 + c];
    yS[c] = fmaxf(y, 0.f);
    __syncthreads();
    if (c < 3) {
        float o = bl2[c];
        for (int k = 0; k < 64; ++k) o += yS[k] * Wl2[k * 3 + c];
        out[g * 3 + c] = o;
    }
}

extern "C" void kernel_launch(void* const* d_in, const int* in_sizes, int n_in,
                              void* d_out, int out_size, void* d_ws, size_t ws_size,
                              hipStream_t stream) {
    const float* x     = (const float*)d_in[0];
    const int*   eid   = (const int*)d_in[1];
    const float* attr  = (const float*)d_in[2];
    const int*   batch = (const int*)d_in[3];
    const float* Wemb  = (const float*)d_in[4];
    const float* bemb  = (const float*)d_in[5];
    const float* W1    = (const float*)d_in[6];
    const float* b1    = (const float*)d_in[7];
    const float* W2    = (const float*)d_in[8];
    const float* W3    = (const float*)d_in[9];
    const float* b3    = (const float*)d_in[10];
    const float* gamma = (const float*)d_in[11];
    const float* beta  = (const float*)d_in[12];
    const float* Wl1   = (const float*)d_in[13];
    const float* bl1   = (const float*)d_in[14];
    const float* Wl2   = (const float*)d_in[15];
    const float* bl2   = (const float*)d_in[16];

    int N = in_sizes[3];
    int E = in_sizes[2];
    int L = in_sizes[7] / 64;
    int G = out_size / 3;

    const int* src = eid;
    const int* dst = eid + E;

    float* ws      = (float*)d_ws;
    float* h       = ws;                       // N*64
    float* S       = h + (size_t)N * 64;       // N*64
    float* degw    = S + (size_t)N * 64;       // N
    float* g4      = degw + N;                 // N*4
    float* bnstats = g4 + (size_t)N * 4;       // 3*128 (per-layer slots)
    float* gsums   = bnstats + 3 * 128;        // G*64
    int*   gbase   = (int*)(gsums + (size_t)G * 64);  // NB+1 (reuses old deg slot, N ints)
    int*   rowptr  = gbase + N;                // N+2
    int*   gcnt    = rowptr + (N + 2);         // 1024
    int*   gcur    = gcnt + 1024;              // 1024 (bucket cursors)
    unsigned long long* edata = (unsigned long long*)(gcur + 1024);  // E
    unsigned long long* tmp   = edata + E;                           // E
    unsigned short* a16 = (unsigned short*)(((uintptr_t)(tmp + E) + 15) & ~(uintptr_t)15);  // N*64 fp16

    int NB = (N + 255) >> 8;  // 256-node buckets (requires N < 2^24, NB <= 1024)

    // ---- CSR build + two-level counting sort of edges by dst (no per-edge
    // global atomics: LDS-aggregated bucket counts + per-bucket LDS histograms) --
    hipMemsetAsync(gcnt, 0, 1024 * sizeof(int), stream);
    hipMemsetAsync(bnstats, 0, 3 * 128 * sizeof(float), stream);
    k_countA<<<(E + ABLK - 1) / ABLK, 1024, 0, stream>>>(dst, gcnt, E, N);
    k_scanbuckets<<<1, 1024, 0, stream>>>(gcnt, gbase, gcur, rowptr, E, N);
    k_binA<<<(E + ABLK - 1) / ABLK, 1024, 0, stream>>>(src, dst, attr, gcur, tmp, E, N);
    k_binB3<<<NB, 256, 0, stream>>>(gbase, tmp, edata, rowptr, N);

    // ---- layers ----
    int gGrid = (N * 64 + 255) / 256;
    for (int l = 0; l < L; ++l) {
        if (l == 0) {
            // layer 0: 4-channel gather on raw x; S0/x0 reconstructed in update
            k_gather4<<<gGrid, 256, 0, stream>>>(rowptr, edata, x, g4, degw, N);
            k_update<0, 1><<<1024, 512, 0, stream>>>(S, h, degw, x, g4, Wemb, bemb,
                                                     nullptr,
                                                     W1, b1, W2, W3, b3, bnstats, N);
        } else {
            k_gather16<<<gGrid, 256, 0, stream>>>(rowptr, edata, a16, S, N);
            k_update<1, 0><<<1024, 512, 0, stream>>>(S, h, degw, nullptr, nullptr,
                                                     nullptr, nullptr, a16,
                                                     W1 + (size_t)l * 4096, b1 + (size_t)l * 64,
                                                     W2 + (size_t)l * 4096, W3 + (size_t)l * 4096,
                                                     b3 + (size_t)l * 64,
                                                     bnstats + (size_t)l * 128, N);
        }
        if (l + 1 < L) {
            k_act<<<1024, 256, 0, stream>>>(h, bnstats + (size_t)l * 128,
                                            gamma + (size_t)l * 64, beta + (size_t)l * 64,
                                            a16, N);
        }
    }

    // ---- pool (applies final BN affine + relu lazily) + head ----
    hipMemsetAsync(gsums, 0, (size_t)G * 64 * sizeof(float), stream);
    k_poolsum<<<(N + POOL_TILE - 1) / POOL_TILE, 256, 0, stream>>>(
        h, batch, bnstats + (size_t)(L - 1) * 128, gamma + (size_t)(L - 1) * 64,
        beta + (size_t)(L - 1) * 64, gsums, N);
    k_head<<<G, 64, 0, stream>>>(gsums, batch, Wl1, bl1, Wl2, bl2, (float*)d_out, N);
}

// Round 12
// 361.685 us; speedup vs baseline: 1.0937x; 1.0937x over previous
//
#include <hip/hip_runtime.h>

#define BN_EPS 1e-5f

typedef __attribute__((ext_vector_type(8))) short bf16x8;
typedef __attribute__((ext_vector_type(4))) float f32x4;

#define ABLK 8192

// ---- sort pass A0: bucket counts via LDS histogram (dst>>8), one global
// atomicAdd per (block,bucket) instead of per edge. ----
__global__ __launch_bounds__(1024) void k_countA(const int* __restrict__ dst,
                                                 int* __restrict__ gcnt, int E, int N) {
    __shared__ int hist[1024];
    int tid = threadIdx.x;
    int NB = (N + 255) >> 8;
    int e0 = blockIdx.x * ABLK;
    int e1 = e0 + ABLK; if (e1 > E) e1 = E;
    for (int i = tid; i < NB; i += 1024) hist[i] = 0;
    __syncthreads();
    for (int e = e0 + tid; e < e1; e += 1024) atomicAdd(&hist[dst[e] >> 8], 1);
    __syncthreads();
    for (int b = tid; b < NB; b += 1024) {
        int hc = hist[b];
        if (hc) atomicAdd(&gcnt[b], hc);
    }
}

// ---- sort pass A1: exclusive scan of bucket counts -> bucket bases + cursors --
__global__ __launch_bounds__(1024) void k_scanbuckets(const int* __restrict__ gcnt,
                                                      int* __restrict__ gbase,
                                                      int* __restrict__ gcur,
                                                      int* __restrict__ rowptr,
                                                      int E, int N) {
    __shared__ int t[1024];
    int tid = threadIdx.x;
    int NB = (N + 255) >> 8;
    int v = (tid < NB) ? gcnt[tid] : 0;
    t[tid] = v;
    __syncthreads();
    for (int d = 1; d < 1024; d <<= 1) {
        int u = (tid >= d) ? t[tid - d] : 0;
        __syncthreads();
        t[tid] += u;
        __syncthreads();
    }
    int ex = t[tid] - v;  // exclusive
    if (tid < NB) { gbase[tid] = ex; gcur[tid] = ex; }
    if (tid == 0) { gbase[NB] = E; rowptr[N] = E; }
}

// ------- sort pass A: partition edges into 256-node buckets (requires N < 2^24) -
// Payload: [attr:32 | dst&255:8 | src:24]
__global__ __launch_bounds__(1024) void k_binA(const int* __restrict__ src,
                                               const int* __restrict__ dst,
                                               const float* __restrict__ attr,
                                               int* __restrict__ gcur,
                                               unsigned long long* __restrict__ tmp,
                                               int E, int N) {
    __shared__ int hist[1024];
    __shared__ int lcur[1024];
    int tid = threadIdx.x;
    int NB = (N + 255) >> 8;  // <= 1024 for N <= 262144
    int e0 = blockIdx.x * ABLK;
    int e1 = e0 + ABLK; if (e1 > E) e1 = E;
    for (int i = tid; i < NB; i += 1024) hist[i] = 0;
    __syncthreads();
    for (int e = e0 + tid; e < e1; e += 1024) atomicAdd(&hist[dst[e] >> 8], 1);
    __syncthreads();
    for (int b = tid; b < NB; b += 1024) {
        int hc = hist[b];
        lcur[b] = hc ? atomicAdd(&gcur[b], hc) : 0;
    }
    __syncthreads();
    for (int e = e0 + tid; e < e1; e += 1024) {
        int d = dst[e];
        int pos = atomicAdd(&lcur[d >> 8], 1);
        unsigned long long p = ((unsigned long long)__float_as_uint(attr[e]) << 32) |
                               ((unsigned long long)(d & 255) << 24) |
                               (unsigned int)src[e];
        tmp[pos] = p;
    }
}

// ------- sort pass B: per bucket, LDS histogram of dst&255 -> rowptr (no global
// atomics for degree counting), then exact placement via LDS cursors.
// Final edata word: [attr_fp32:32 | src:24] (plain src index; consumers shift).
__global__ __launch_bounds__(256) void k_binB3(const int* __restrict__ gbase,
                                               const unsigned long long* __restrict__ tmp,
                                               unsigned long long* __restrict__ edata,
                                               int* __restrict__ rowptr, int N) {
    __shared__ int cnt[256];
    __shared__ int scn[256];
    __shared__ int cur[256];
    int b = blockIdx.x;
    int tid = threadIdx.x;
    int nb0 = b << 8;
    int beg = gbase[b], end = gbase[b + 1];
    cnt[tid] = 0;
    __syncthreads();
    for (int e = beg + tid; e < end; e += 256)
        atomicAdd(&cnt[(int)((tmp[e] >> 24) & 255)], 1);
    __syncthreads();
    int v = cnt[tid];
    scn[tid] = v;
    __syncthreads();
    for (int d = 1; d < 256; d <<= 1) {
        int u = (tid >= d) ? scn[tid - d] : 0;
        __syncthreads();
        scn[tid] += u;
        __syncthreads();
    }
    int ex = beg + scn[tid] - v;  // exclusive within bucket + base
    int node = nb0 + tid;
    if (node < N) rowptr[node] = ex;
    cur[tid] = ex;
    __syncthreads();
    for (int e = beg + tid; e < end; e += 256) {
        unsigned long long p = tmp[e];
        int dl = (int)((p >> 24) & 255);
        int pos = atomicAdd(&cur[dl], 1);
        edata[pos] = (p & 0xFFFFFFFF00000000ull) | (p & 0xFFFFFFull);
    }
}

// ---- inline BN scale/shift from raw stats ----
__device__ __forceinline__ void bn_coeff(const float* bs, const float* gam,
                                         const float* bet, int c, float inv_n,
                                         float& sc, float& sh) {
    float mean = bs[c] * inv_n;
    float var = bs[64 + c] * inv_n - mean * mean;
    sc = gam[c] * rsqrtf(fmaxf(var, 0.f) + BN_EPS);
    sh = bet[c] - mean * sc;
}

__device__ __forceinline__ float h16lo(unsigned u) {
    return (float)__builtin_bit_cast(_Float16, (unsigned short)(u & 0xFFFFu));
}
__device__ __forceinline__ float h16hi(unsigned u) {
    return (float)__builtin_bit_cast(_Float16, (unsigned short)(u >> 16));
}

// ---- layer-0 gather on raw x (N x 4): one WAVE per node, 16 edge slots x 4 ch.
// Coalesced edata reads; shfl-reduce over edge slots. ----
__global__ __launch_bounds__(256) void k_gather4(const int* __restrict__ rowptr,
                                                 const unsigned long long* __restrict__ edata,
                                                 const float* __restrict__ x,
                                                 float* __restrict__ g4,
                                                 float* __restrict__ degw, int N) {
    int wid = (blockIdx.x * blockDim.x + threadIdx.x) >> 6;  // one wave per node
    if (wid >= N) return;
    int lane = threadIdx.x & 63;
    int es = lane >> 2;   // edge slot 0..15
    int ch = lane & 3;
    int beg = rowptr[wid], end = rowptr[wid + 1];
    int len = end - beg;
    float acc = 0.f, wsum = 0.f;
    for (int base = 0; base < len; base += 16) {
        int idx = base + es;
        unsigned long long p = edata[beg + (idx < len ? idx : (len ? len - 1 : 0))];
        float w = (idx < len) ? __uint_as_float((unsigned)(p >> 32)) : 0.f;
        unsigned srcb = (unsigned)p;  // src (bits 24-31 are zero)
        float v = x[(size_t)srcb * 4 + ch];
        acc = fmaf(w, v, acc);
        wsum += w;
    }
    acc += __shfl_xor(acc, 4);  wsum += __shfl_xor(wsum, 4);
    acc += __shfl_xor(acc, 8);  wsum += __shfl_xor(wsum, 8);
    acc += __shfl_xor(acc, 16); wsum += __shfl_xor(wsum, 16);
    acc += __shfl_xor(acc, 32); wsum += __shfl_xor(wsum, 32);
    if (es == 0) {
        g4[(size_t)wid * 4 + ch] = acc;
        if (ch == 0) degw[wid] = wsum;
    }
}

// ---- activation materialization: a16 = fp16(relu(BN(h))), linear [N][64] ----
__global__ __launch_bounds__(256) void k_act(const float* __restrict__ h,
                                             const float* __restrict__ bs,
                                             const float* __restrict__ gam,
                                             const float* __restrict__ bet,
                                             unsigned short* __restrict__ a16,
                                             int N) {
    __shared__ float scS[64], shS[64];
    int tid = threadIdx.x;
    if (tid < 64) {
        float sc, sh;
        bn_coeff(bs, gam, bet, tid, 1.f / (float)N, sc, sh);
        scS[tid] = sc; shS[tid] = sh;
    }
    __syncthreads();
    int c0 = (tid & 15) << 2;
    float4 scv = *(const float4*)&scS[c0];
    float4 shv = *(const float4*)&shS[c0];
    int total = N << 4;  // N*64/4 chunks
    for (int t = blockIdx.x * 256 + tid; t < total; t += gridDim.x * 256) {
        float4 v = *(const float4*)&h[(size_t)t * 4];
        float r0 = fmaxf(fmaf(v.x, scv.x, shv.x), 0.f);
        float r1 = fmaxf(fmaf(v.y, scv.y, shv.y), 0.f);
        float r2 = fmaxf(fmaf(v.z, scv.z, shv.z), 0.f);
        float r3 = fmaxf(fmaf(v.w, scv.w, shv.w), 0.f);
        unsigned q0 = __builtin_bit_cast(unsigned short, (_Float16)r0);
        unsigned q1 = __builtin_bit_cast(unsigned short, (_Float16)r1);
        unsigned q2 = __builtin_bit_cast(unsigned short, (_Float16)r2);
        unsigned q3 = __builtin_bit_cast(unsigned short, (_Float16)r3);
        uint2 o; o.x = q0 | (q1 << 16); o.y = q2 | (q3 << 16);
        *(uint2*)&a16[(size_t)t * 4] = o;
    }
}

// ------- pull gather from pre-activated fp16: S[n] = sum_e w_e * a16[src_e] ----
// One wave per node, organized as 4 edge-streams x 16 channel-quads. Each lane
// loads uint2 (8B = 4 fp16); a stream's 16 lanes cover the full 128B row.
// 4 float4 acc chains -> ~16 outstanding row reads per wave. Streams combined
// via shfl_xor(16/32); lanes 0-15 store float4.
__global__ __launch_bounds__(256) void k_gather16(const int* __restrict__ rowptr,
                                                  const unsigned long long* __restrict__ edata,
                                                  const unsigned short* __restrict__ a16,
                                                  float* __restrict__ S, int N) {
    int wid = (blockIdx.x * blockDim.x + threadIdx.x) >> 6;  // one wave per node
    if (wid >= N) return;
    int lane = threadIdx.x & 63;
    int s = lane >> 4;           // edge stream 0..3
    int q = lane & 15;           // channel quad (channels 4q..4q+3)
    unsigned c8 = (unsigned)(q << 3);  // byte offset of the quad in a 128B row

    int beg = rowptr[wid], end = rowptr[wid + 1];
    int len = end - beg;
    float4 acc[4];
#pragma unroll
    for (int j = 0; j < 4; ++j) { acc[j].x = 0.f; acc[j].y = 0.f; acc[j].z = 0.f; acc[j].w = 0.f; }
    int nFull = len & ~15;
    for (int base = 0; base < nFull; base += 16) {
#pragma unroll
        for (int j = 0; j < 4; ++j) {
            unsigned long long p = edata[beg + base + 4 * j + s];
            float w = __uint_as_float((unsigned)(p >> 32));
            unsigned off = (((unsigned)p) << 7) | c8;
            uint2 v = *(const uint2*)((const char*)a16 + off);
            acc[j].x = fmaf(w, h16lo(v.x), acc[j].x);
            acc[j].y = fmaf(w, h16hi(v.x), acc[j].y);
            acc[j].z = fmaf(w, h16lo(v.y), acc[j].z);
            acc[j].w = fmaf(w, h16hi(v.y), acc[j].w);
        }
    }
    if (nFull < len) {
#pragma unroll
        for (int j = 0; j < 4; ++j) {
            int idx = nFull + 4 * j + s;
            unsigned long long p = edata[beg + (idx < len ? idx : (len ? len - 1 : 0))];
            float w = (idx < len) ? __uint_as_float((unsigned)(p >> 32)) : 0.f;
            unsigned off = (((unsigned)p) << 7) | c8;
            uint2 v = *(const uint2*)((const char*)a16 + off);
            acc[j].x = fmaf(w, h16lo(v.x), acc[j].x);
            acc[j].y = fmaf(w, h16hi(v.x), acc[j].y);
            acc[j].z = fmaf(w, h16lo(v.y), acc[j].z);
            acc[j].w = fmaf(w, h16hi(v.y), acc[j].w);
        }
    }
    float4 r;
    r.x = (acc[0].x + acc[1].x) + (acc[2].x + acc[3].x);
    r.y = (acc[0].y + acc[1].y) + (acc[2].y + acc[3].y);
    r.z = (acc[0].z + acc[1].z) + (acc[2].z + acc[3].z);
    r.w = (acc[0].w + acc[1].w) + (acc[2].w + acc[3].w);
    r.x += __shfl_xor(r.x, 16); r.y += __shfl_xor(r.y, 16);
    r.z += __shfl_xor(r.z, 16); r.w += __shfl_xor(r.w, 16);
    r.x += __shfl_xor(r.x, 32); r.y += __shfl_xor(r.y, 32);
    r.z += __shfl_xor(r.z, 32); r.w += __shfl_xor(r.w, 32);
    if (s == 0) {
        *(float4*)&S[(size_t)wid * 64 + (q << 2)] = r;
    }
}

// ---- bf16x3 split helpers ----
__device__ __forceinline__ void split_pack8(const float* v, uint4& H, uint4& L) {
    unsigned hb[8], lb[8];
#pragma unroll
    for (int j = 0; j < 8; ++j) {
        unsigned b = __float_as_uint(v[j]);
        unsigned rb = (b + 0x7FFFu + ((b >> 16) & 1u)) & 0xFFFF0000u;  // RNE bf16
        hb[j] = rb >> 16;
        float lo = v[j] - __uint_as_float(rb);  // exact
        lb[j] = __float_as_uint(lo) >> 16;
    }
    H.x = hb[0] | (hb[1] << 16); H.y = hb[2] | (hb[3] << 16);
    H.z = hb[4] | (hb[5] << 16); H.w = hb[6] | (hb[7] << 16);
    L.x = lb[0] | (lb[1] << 16); L.y = lb[2] | (lb[3] << 16);
    L.z = lb[4] | (lb[5] << 16); L.w = lb[6] | (lb[7] << 16);
}

__device__ __forceinline__ void split_frag(const float* w, bf16x8& hi, bf16x8& lo) {
#pragma unroll
    for (int j = 0; j < 8; ++j) {
        unsigned b = __float_as_uint(w[j]);
        unsigned rb = (b + 0x7FFFu + ((b >> 16) & 1u)) & 0xFFFF0000u;
        hi[j] = (short)(rb >> 16);
        float lof = w[j] - __uint_as_float(rb);
        lo[j] = (short)(__float_as_uint(lof) >> 16);
    }
}

// --- h_raw_out = S@W1 + x@W3 - dw*(x@W2) + dw*b1 + b3 via bf16x3 MFMA.
// LDS staging uses a bijective XOR swizzle unit^=(unit>>4)&7 on 16B units,
// applied on BOTH the write (slot) and read (base) sides: kills the 8-way
// staging-write bank conflict (2.8M cycles/dispatch in r10 PMC) while keeping
// reads uniform across bank groups. PRE=1: x_i from fp16 a16 (exact split).
// EMB=1 (layer 0): S/x rows reconstructed from g4/x via Wemb during staging.
template <int PRE, int EMB>
__global__ __launch_bounds__(512) void k_update(
    const float* __restrict__ S, float* __restrict__ h,
    const float* __restrict__ degw,
    const float* __restrict__ xin, const float* __restrict__ g4,
    const float* __restrict__ Wemb, const float* __restrict__ bemb,
    const unsigned short* __restrict__ a16,
    const float* __restrict__ W1, const float* __restrict__ b1,
    const float* __restrict__ W2, const float* __restrict__ W3,
    const float* __restrict__ b3,
    float* __restrict__ bnstats, int N) {
    // [Shi | Slo | Hhi | Hlo], 4096 ushorts (8KB) each = 32KB
    __shared__ __align__(16) unsigned short sA[16384];
    __shared__ float dwS[64];

    int tid = threadIdx.x;
    int lane = tid & 63;
    int wv = tid >> 6;            // wave 0..7
    int mg = wv >> 2;             // row-group: rows mg*32 .. mg*32+31
    int nb = wv & 3;              // col-block: cols nb*16 .. nb*16+15
    int c = (nb << 4) | (lane & 15);
    int krow = (lane >> 4) << 3;  // k-offset of this lane's fragment elems

    // ---- B fragments (weights) in registers, one-time ----
    bf16x8 B1h[2], B1l[2], B2h[2], B2l[2], B3h[2], B3l[2];
#pragma unroll
    for (int ks = 0; ks < 2; ++ks) {
        float w1v[8], w2v[8], w3v[8];
        int kb = ks * 32 + krow;
#pragma unroll
        for (int j = 0; j < 8; ++j) {
            int idx = (kb + j) * 64 + c;
            w1v[j] = W1[idx];
            w2v[j] = W2[idx];
            w3v[j] = W3[idx];
        }
        split_frag(w1v, B1h[ks], B1l[ks]);
        split_frag(w2v, B2h[ks], B2l[ks]);
        split_frag(w3v, B3h[ks], B3l[ks]);
    }
    float b1c = b1[c], b3c = b3[c];

    // ---- staging role: thread handles row r, k-chunk kg (8 consecutive k) ----
    int r = tid >> 3;   // 0..63
    int kg = tid & 7;   // 0..7
    int k0 = kg << 3;
    int unit0 = (((r >> 4) * 2 + (kg >> 2)) * 64) + ((kg & 3) << 4) + (r & 15);
    int slot = (unit0 ^ ((unit0 >> 4) & 7)) * 8;  // swizzled 16B-unit address

    float we0[8], we1[8], we2[8], we3[8], bev[8];
    if (EMB) {
#pragma unroll
        for (int j = 0; j < 8; ++j) {
            we0[j] = Wemb[k0 + j];
            we1[j] = Wemb[64 + k0 + j];
            we2[j] = Wemb[128 + k0 + j];
            we3[j] = Wemb[192 + k0 + j];
            bev[j] = bemb[k0 + j];
        }
    }

    float bsum = 0.f, bsq = 0.f;
    int numTiles = (N + 63) >> 6;
    for (int tile = blockIdx.x; tile < numTiles; tile += gridDim.x) {
        int n0 = tile << 6;
        __syncthreads();  // protect LDS from previous iteration's readers
        {
            int n = n0 + r;
            float sv[8], hv[8];
            if (n < N) {
                if (EMB) {
                    float4 g = *(const float4*)&g4[(size_t)n * 4];
                    float4 xr = *(const float4*)&xin[(size_t)n * 4];
                    float dw = degw[n];
#pragma unroll
                    for (int j = 0; j < 8; ++j) {
                        sv[j] = fmaf(g.x, we0[j], fmaf(g.y, we1[j],
                                 fmaf(g.z, we2[j], fmaf(g.w, we3[j], dw * bev[j]))));
                        hv[j] = fmaf(xr.x, we0[j], fmaf(xr.y, we1[j],
                                 fmaf(xr.z, we2[j], fmaf(xr.w, we3[j], bev[j]))));
                    }
                } else {
                    const float* Sp = &S[(size_t)n * 64 + k0];
                    float4 s0_ = *(const float4*)Sp;
                    float4 s1_ = *(const float4*)(Sp + 4);
                    sv[0]=s0_.x; sv[1]=s0_.y; sv[2]=s0_.z; sv[3]=s0_.w;
                    sv[4]=s1_.x; sv[5]=s1_.y; sv[6]=s1_.z; sv[7]=s1_.w;
                    uint4 hp = *(const uint4*)((const char*)a16 + (((size_t)n) << 7) + (k0 << 1));
                    hv[0] = h16lo(hp.x); hv[1] = h16hi(hp.x);
                    hv[2] = h16lo(hp.y); hv[3] = h16hi(hp.y);
                    hv[4] = h16lo(hp.z); hv[5] = h16hi(hp.z);
                    hv[6] = h16lo(hp.w); hv[7] = h16hi(hp.w);
                }
            } else {
#pragma unroll
                for (int j = 0; j < 8; ++j) { sv[j] = 0.f; hv[j] = 0.f; }
            }
            uint4 H, L;
            split_pack8(sv, H, L);
            *(uint4*)&sA[slot] = H;
            *(uint4*)&sA[4096 + slot] = L;
            split_pack8(hv, H, L);
            *(uint4*)&sA[8192 + slot] = H;
            *(uint4*)&sA[12288 + slot] = L;
            if (tid < 64) dwS[tid] = (n0 + tid < N) ? degw[n0 + tid] : 0.f;
        }
        __syncthreads();
        // ---- MFMA: acc over K=64 (2 K-steps), 2 M-subtiles per wave ----
        f32x4 accP[2] = {{0.f,0.f,0.f,0.f},{0.f,0.f,0.f,0.f}};
        f32x4 accN[2] = {{0.f,0.f,0.f,0.f},{0.f,0.f,0.f,0.f}};
#pragma unroll
        for (int ks = 0; ks < 2; ++ks) {
#pragma unroll
            for (int mtg = 0; mtg < 2; ++mtg) {
                int mt = mg * 2 + mtg;
                int ub = (mt * 2 + ks) * 64 + lane;
                int base = (ub ^ ((ub >> 4) & 7)) * 8;  // swizzled read
                bf16x8 aSh = *(const bf16x8*)&sA[base];
                bf16x8 aSl = *(const bf16x8*)&sA[4096 + base];
                bf16x8 aHh = *(const bf16x8*)&sA[8192 + base];
                bf16x8 aHl = *(const bf16x8*)&sA[12288 + base];
                f32x4 p = accP[mtg], q = accN[mtg];
                p = __builtin_amdgcn_mfma_f32_16x16x32_bf16(aSh, B1h[ks], p, 0, 0, 0);
                p = __builtin_amdgcn_mfma_f32_16x16x32_bf16(aSl, B1h[ks], p, 0, 0, 0);
                p = __builtin_amdgcn_mfma_f32_16x16x32_bf16(aSh, B1l[ks], p, 0, 0, 0);
                p = __builtin_amdgcn_mfma_f32_16x16x32_bf16(aHh, B3h[ks], p, 0, 0, 0);
                p = __builtin_amdgcn_mfma_f32_16x16x32_bf16(aHl, B3h[ks], p, 0, 0, 0);
                p = __builtin_amdgcn_mfma_f32_16x16x32_bf16(aHh, B3l[ks], p, 0, 0, 0);
                q = __builtin_amdgcn_mfma_f32_16x16x32_bf16(aHh, B2h[ks], q, 0, 0, 0);
                q = __builtin_amdgcn_mfma_f32_16x16x32_bf16(aHl, B2h[ks], q, 0, 0, 0);
                q = __builtin_amdgcn_mfma_f32_16x16x32_bf16(aHh, B2l[ks], q, 0, 0, 0);
                accP[mtg] = p; accN[mtg] = q;
            }
        }
        // ---- epilogue: C layout col=lane&15, row=(lane>>4)*4+j ----
#pragma unroll
        for (int mtg = 0; mtg < 2; ++mtg) {
            int rowb = mg * 32 + mtg * 16 + ((lane >> 4) << 2);
            float4 dwv = *(const float4*)&dwS[rowb];
            float dwa[4] = {dwv.x, dwv.y, dwv.z, dwv.w};
#pragma unroll
            for (int j = 0; j < 4; ++j) {
                int n = n0 + rowb + j;
                if (n < N) {
                    float val = accP[mtg][j] - dwa[j] * accN[mtg][j] + dwa[j] * b1c + b3c;
                    h[(size_t)n * 64 + c] = val;  // raw (pre-BN)
                    bsum += val;
                    bsq += val * val;
                }
            }
        }
    }
    // ---- BN stats reduction (reuse sA as 1024 floats) ----
    __syncthreads();
    float* red = (float*)sA;
    red[tid] = bsum;
    red[512 + tid] = bsq;
    __syncthreads();
    if (tid < 64) {
        int nb_ = tid >> 4, cl = tid & 15;
        float s = 0.f, qq = 0.f;
#pragma unroll
        for (int i = 0; i < 8; ++i) {
            int t = ((i & 1) << 8) + (nb_ << 6) + ((i >> 1) << 4) + cl;
            s += red[t];
            qq += red[512 + t];
        }
        atomicAdd(&bnstats[tid], s);
        atomicAdd(&bnstats[64 + tid], qq);
    }
}

// ------- pool phase 1: per-graph sums of act(h_raw), sorted-run + atomics -------
#define POOL_TILE 128
__global__ __launch_bounds__(256) void k_poolsum(const float* __restrict__ h,
                                                 const int* __restrict__ batch,
                                                 const float* __restrict__ bsp,
                                                 const float* __restrict__ gamp,
                                                 const float* __restrict__ betp,
                                                 float* __restrict__ gsums, int N) {
    int tid = threadIdx.x;
    int c = tid & 63, q = tid >> 6;
    float sc, sh_;
    bn_coeff(bsp, gamp, betp, c, 1.f / (float)N, sc, sh_);
    int n0 = blockIdx.x * POOL_TILE;
    int nEnd = n0 + POOL_TILE; if (nEnd > N) nEnd = N;
    int g = -1;
    float acc = 0.f;
    for (int n = n0 + q; n < nEnd; n += 4) {
        int b = batch[n];
        if (b != g) {
            if (g >= 0) atomicAdd(&gsums[(size_t)g * 64 + c], acc);
            g = b; acc = 0.f;
        }
        acc += fmaxf(fmaf(h[(size_t)n * 64 + c], sc, sh_), 0.f);
    }
    if (g >= 0) atomicAdd(&gsums[(size_t)g * 64 + c], acc);
}

// ------- pool phase 2: divide by count + MLP head (one 64-thread block / graph) -
__global__ void k_head(const float* __restrict__ gsums, const int* __restrict__ batch,
                       const float* __restrict__ Wl1, const float* __restrict__ bl1,
                       const float* __restrict__ Wl2, const float* __restrict__ bl2,
                       float* __restrict__ out, int N) {
    int g = blockIdx.x;
    int c = threadIdx.x;  // 64 threads
    int lo = 0, hi = N;
    while (lo < hi) { int mid = (lo + hi) >> 1; if (batch[mid] < g) lo = mid + 1; else hi = mid; }
    int start = lo;
    hi = N;
    while (lo < hi) { int mid = (lo + hi) >> 1; if (batch[mid] < g + 1) lo = mid + 1; else hi = mid; }
    int cnt = lo - start;
    float denom = (float)(cnt > 0 ? cnt : 1);
    __shared__ float gS[64], yS[64];
    gS[c] = gsums[(size_t)g * 64 + c] / denom;
    __syncthreads();
    float y = bl1[c];
    for (int k = 0; k < 64; ++k) y += gS[k] * Wl1[k * 64 + c];
    yS[c] = fmaxf(y, 0.f);
    __syncthreads();
    if (c < 3) {
        float o = bl2[c];
        for (int k = 0; k < 64; ++k) o += yS[k] * Wl2[k * 3 + c];
        out[g * 3 + c] = o;
    }
}

extern "C" void kernel_launch(void* const* d_in, const int* in_sizes, int n_in,
                              void* d_out, int out_size, void* d_ws, size_t ws_size,
                              hipStream_t stream) {
    const float* x     = (const float*)d_in[0];
    const int*   eid   = (const int*)d_in[1];
    const float* attr  = (const float*)d_in[2];
    const int*   batch = (const int*)d_in[3];
    const float* Wemb  = (const float*)d_in[4];
    const float* bemb  = (const float*)d_in[5];
    const float* W1    = (const float*)d_in[6];
    const float* b1    = (const float*)d_in[7];
    const float* W2    = (const float*)d_in[8];
    const float* W3    = (const float*)d_in[9];
    const float* b3    = (const float*)d_in[10];
    const float* gamma = (const float*)d_in[11];
    const float* beta  = (const float*)d_in[12];
    const float* Wl1   = (const float*)d_in[13];
    const float* bl1   = (const float*)d_in[14];
    const float* Wl2   = (const float*)d_in[15];
    const float* bl2   = (const float*)d_in[16];

    int N = in_sizes[3];
    int E = in_sizes[2];
    int L = in_sizes[7] / 64;
    int G = out_size / 3;

    const int* src = eid;
    const int* dst = eid + E;

    float* ws      = (float*)d_ws;
    float* h       = ws;                       // N*64
    float* S       = h + (size_t)N * 64;       // N*64
    float* degw    = S + (size_t)N * 64;       // N
    float* g4      = degw + N;                 // N*4
    float* bnstats = g4 + (size_t)N * 4;       // 3*128 (per-layer slots)
    float* gsums   = bnstats + 3 * 128;        // G*64
    int*   gbase   = (int*)(gsums + (size_t)G * 64);  // NB+1 (reuses old deg slot, N ints)
    int*   rowptr  = gbase + N;                // N+2
    int*   gcnt    = rowptr + (N + 2);         // 1024
    int*   gcur    = gcnt + 1024;              // 1024 (bucket cursors)
    unsigned long long* edata = (unsigned long long*)(gcur + 1024);  // E
    unsigned long long* tmp   = edata + E;                           // E
    unsigned short* a16 = (unsigned short*)(((uintptr_t)(tmp + E) + 15) & ~(uintptr_t)15);  // N*64 fp16

    int NB = (N + 255) >> 8;  // 256-node buckets (requires N < 2^24, NB <= 1024)

    // ---- CSR build + two-level counting sort of edges by dst (no per-edge
    // global atomics: LDS-aggregated bucket counts + per-bucket LDS histograms) --
    hipMemsetAsync(gcnt, 0, 1024 * sizeof(int), stream);
    hipMemsetAsync(bnstats, 0, 3 * 128 * sizeof(float), stream);
    k_countA<<<(E + ABLK - 1) / ABLK, 1024, 0, stream>>>(dst, gcnt, E, N);
    k_scanbuckets<<<1, 1024, 0, stream>>>(gcnt, gbase, gcur, rowptr, E, N);
    k_binA<<<(E + ABLK - 1) / ABLK, 1024, 0, stream>>>(src, dst, attr, gcur, tmp, E, N);
    k_binB3<<<NB, 256, 0, stream>>>(gbase, tmp, edata, rowptr, N);

    // ---- layers ----
    int gGrid = (N * 64 + 255) / 256;
    for (int l = 0; l < L; ++l) {
        if (l == 0) {
            // layer 0: 4-channel gather on raw x; S0/x0 reconstructed in update
            k_gather4<<<gGrid, 256, 0, stream>>>(rowptr, edata, x, g4, degw, N);
            k_update<0, 1><<<512, 512, 0, stream>>>(S, h, degw, x, g4, Wemb, bemb,
                                                    nullptr,
                                                    W1, b1, W2, W3, b3, bnstats, N);
        } else {
            k_gather16<<<gGrid, 256, 0, stream>>>(rowptr, edata, a16, S, N);
            k_update<1, 0><<<512, 512, 0, stream>>>(S, h, degw, nullptr, nullptr,
                                                    nullptr, nullptr, a16,
                                                    W1 + (size_t)l * 4096, b1 + (size_t)l * 64,
                                                    W2 + (size_t)l * 4096, W3 + (size_t)l * 4096,
                                                    b3 + (size_t)l * 64,
                                                    bnstats + (size_t)l * 128, N);
        }
        if (l + 1 < L) {
            k_act<<<1024, 256, 0, stream>>>(h, bnstats + (size_t)l * 128,
                                            gamma + (size_t)l * 64, beta + (size_t)l * 64,
                                            a16, N);
        }
    }

    // ---- pool (applies final BN affine + relu lazily) + head ----
    hipMemsetAsync(gsums, 0, (size_t)G * 64 * sizeof(float), stream);
    k_poolsum<<<(N + POOL_TILE - 1) / POOL_TILE, 256, 0, stream>>>(
        h, batch, bnstats + (size_t)(L - 1) * 128, gamma + (size_t)(L - 1) * 64,
        beta + (size_t)(L - 1) * 64, gsums, N);
    k_head<<<G, 64, 0, stream>>>(gsums, batch, Wl1, bl1, Wl2, bl2, (float*)d_out, N);
}

// Round 13
// 356.219 us; speedup vs baseline: 1.1105x; 1.0153x over previous
//
#include <hip/hip_runtime.h>

#define BN_EPS 1e-5f

typedef __attribute__((ext_vector_type(8))) short bf16x8;
typedef __attribute__((ext_vector_type(4))) float f32x4;

#define ABLK 8192

// ---- sort pass A0: bucket counts via LDS histogram (dst>>8), one global
// atomicAdd per (block,bucket) instead of per edge. ----
__global__ __launch_bounds__(1024) void k_countA(const int* __restrict__ dst,
                                                 int* __restrict__ gcnt, int E, int N) {
    __shared__ int hist[1024];
    int tid = threadIdx.x;
    int NB = (N + 255) >> 8;
    int e0 = blockIdx.x * ABLK;
    int e1 = e0 + ABLK; if (e1 > E) e1 = E;
    for (int i = tid; i < NB; i += 1024) hist[i] = 0;
    __syncthreads();
    for (int e = e0 + tid; e < e1; e += 1024) atomicAdd(&hist[dst[e] >> 8], 1);
    __syncthreads();
    for (int b = tid; b < NB; b += 1024) {
        int hc = hist[b];
        if (hc) atomicAdd(&gcnt[b], hc);
    }
}

// ---- sort pass A1: exclusive scan of bucket counts -> bucket bases + cursors --
__global__ __launch_bounds__(1024) void k_scanbuckets(const int* __restrict__ gcnt,
                                                      int* __restrict__ gbase,
                                                      int* __restrict__ gcur,
                                                      int* __restrict__ rowptr,
                                                      int E, int N) {
    __shared__ int t[1024];
    int tid = threadIdx.x;
    int NB = (N + 255) >> 8;
    int v = (tid < NB) ? gcnt[tid] : 0;
    t[tid] = v;
    __syncthreads();
    for (int d = 1; d < 1024; d <<= 1) {
        int u = (tid >= d) ? t[tid - d] : 0;
        __syncthreads();
        t[tid] += u;
        __syncthreads();
    }
    int ex = t[tid] - v;  // exclusive
    if (tid < NB) { gbase[tid] = ex; gcur[tid] = ex; }
    if (tid == 0) { gbase[NB] = E; rowptr[N] = E; }
}

// ------- sort pass A: partition edges into 256-node buckets (requires N < 2^24) -
// Payload: [attr:32 | dst&255:8 | src:24]
__global__ __launch_bounds__(1024) void k_binA(const int* __restrict__ src,
                                               const int* __restrict__ dst,
                                               const float* __restrict__ attr,
                                               int* __restrict__ gcur,
                                               unsigned long long* __restrict__ tmp,
                                               int E, int N) {
    __shared__ int hist[1024];
    __shared__ int lcur[1024];
    int tid = threadIdx.x;
    int NB = (N + 255) >> 8;  // <= 1024 for N <= 262144
    int e0 = blockIdx.x * ABLK;
    int e1 = e0 + ABLK; if (e1 > E) e1 = E;
    for (int i = tid; i < NB; i += 1024) hist[i] = 0;
    __syncthreads();
    for (int e = e0 + tid; e < e1; e += 1024) atomicAdd(&hist[dst[e] >> 8], 1);
    __syncthreads();
    for (int b = tid; b < NB; b += 1024) {
        int hc = hist[b];
        lcur[b] = hc ? atomicAdd(&gcur[b], hc) : 0;
    }
    __syncthreads();
    for (int e = e0 + tid; e < e1; e += 1024) {
        int d = dst[e];
        int pos = atomicAdd(&lcur[d >> 8], 1);
        unsigned long long p = ((unsigned long long)__float_as_uint(attr[e]) << 32) |
                               ((unsigned long long)(d & 255) << 24) |
                               (unsigned int)src[e];
        tmp[pos] = p;
    }
}

// ------- sort pass B: per bucket, LDS histogram of dst&255 -> rowptr (no global
// atomics for degree counting), then exact placement via LDS cursors.
// Final edata word: [attr_fp32:32 | src:24] (plain src index; consumers shift).
__global__ __launch_bounds__(256) void k_binB3(const int* __restrict__ gbase,
                                               const unsigned long long* __restrict__ tmp,
                                               unsigned long long* __restrict__ edata,
                                               int* __restrict__ rowptr, int N) {
    __shared__ int cnt[256];
    __shared__ int scn[256];
    __shared__ int cur[256];
    int b = blockIdx.x;
    int tid = threadIdx.x;
    int nb0 = b << 8;
    int beg = gbase[b], end = gbase[b + 1];
    cnt[tid] = 0;
    __syncthreads();
    for (int e = beg + tid; e < end; e += 256)
        atomicAdd(&cnt[(int)((tmp[e] >> 24) & 255)], 1);
    __syncthreads();
    int v = cnt[tid];
    scn[tid] = v;
    __syncthreads();
    for (int d = 1; d < 256; d <<= 1) {
        int u = (tid >= d) ? scn[tid - d] : 0;
        __syncthreads();
        scn[tid] += u;
        __syncthreads();
    }
    int ex = beg + scn[tid] - v;  // exclusive within bucket + base
    int node = nb0 + tid;
    if (node < N) rowptr[node] = ex;
    cur[tid] = ex;
    __syncthreads();
    for (int e = beg + tid; e < end; e += 256) {
        unsigned long long p = tmp[e];
        int dl = (int)((p >> 24) & 255);
        int pos = atomicAdd(&cur[dl], 1);
        edata[pos] = (p & 0xFFFFFFFF00000000ull) | (p & 0xFFFFFFull);
    }
}

// ---- inline BN scale/shift from raw stats ----
__device__ __forceinline__ void bn_coeff(const float* bs, const float* gam,
                                         const float* bet, int c, float inv_n,
                                         float& sc, float& sh) {
    float mean = bs[c] * inv_n;
    float var = bs[64 + c] * inv_n - mean * mean;
    sc = gam[c] * rsqrtf(fmaxf(var, 0.f) + BN_EPS);
    sh = bet[c] - mean * sc;
}

__device__ __forceinline__ float h16lo(unsigned u) {
    return (float)__builtin_bit_cast(_Float16, (unsigned short)(u & 0xFFFFu));
}
__device__ __forceinline__ float h16hi(unsigned u) {
    return (float)__builtin_bit_cast(_Float16, (unsigned short)(u >> 16));
}
__device__ __forceinline__ unsigned short f2h(float v) {
    return __builtin_bit_cast(unsigned short, (_Float16)v);
}

// ---- layer-0 gather on raw x (N x 4): one WAVE per node, 16 edge slots x 4 ch.
// Coalesced edata reads; shfl-reduce over edge slots. ----
__global__ __launch_bounds__(256) void k_gather4(const int* __restrict__ rowptr,
                                                 const unsigned long long* __restrict__ edata,
                                                 const float* __restrict__ x,
                                                 float* __restrict__ g4,
                                                 float* __restrict__ degw, int N) {
    int wid = (blockIdx.x * blockDim.x + threadIdx.x) >> 6;  // one wave per node
    if (wid >= N) return;
    int lane = threadIdx.x & 63;
    int es = lane >> 2;   // edge slot 0..15
    int ch = lane & 3;
    int beg = rowptr[wid], end = rowptr[wid + 1];
    int len = end - beg;
    float acc = 0.f, wsum = 0.f;
    for (int base = 0; base < len; base += 16) {
        int idx = base + es;
        unsigned long long p = edata[beg + (idx < len ? idx : (len ? len - 1 : 0))];
        float w = (idx < len) ? __uint_as_float((unsigned)(p >> 32)) : 0.f;
        unsigned srcb = (unsigned)p;  // src (bits 24-31 are zero)
        float v = x[(size_t)srcb * 4 + ch];
        acc = fmaf(w, v, acc);
        wsum += w;
    }
    acc += __shfl_xor(acc, 4);  wsum += __shfl_xor(wsum, 4);
    acc += __shfl_xor(acc, 8);  wsum += __shfl_xor(wsum, 8);
    acc += __shfl_xor(acc, 16); wsum += __shfl_xor(wsum, 16);
    acc += __shfl_xor(acc, 32); wsum += __shfl_xor(wsum, 32);
    if (es == 0) {
        g4[(size_t)wid * 4 + ch] = acc;
        if (ch == 0) degw[wid] = wsum;
    }
}

// ---- activation materialization: a16 = fp16(relu(BN(h16))), linear [N][64] ----
__global__ __launch_bounds__(256) void k_act(const unsigned short* __restrict__ h16,
                                             const float* __restrict__ bs,
                                             const float* __restrict__ gam,
                                             const float* __restrict__ bet,
                                             unsigned short* __restrict__ a16,
                                             int N) {
    __shared__ float scS[64], shS[64];
    int tid = threadIdx.x;
    if (tid < 64) {
        float sc, sh;
        bn_coeff(bs, gam, bet, tid, 1.f / (float)N, sc, sh);
        scS[tid] = sc; shS[tid] = sh;
    }
    __syncthreads();
    int c0 = (tid & 15) << 2;
    float4 scv = *(const float4*)&scS[c0];
    float4 shv = *(const float4*)&shS[c0];
    int total = N << 4;  // N*64/4 chunks
    for (int t = blockIdx.x * 256 + tid; t < total; t += gridDim.x * 256) {
        uint2 hv = *(const uint2*)&h16[(size_t)t * 4];
        float r0 = fmaxf(fmaf(h16lo(hv.x), scv.x, shv.x), 0.f);
        float r1 = fmaxf(fmaf(h16hi(hv.x), scv.y, shv.y), 0.f);
        float r2 = fmaxf(fmaf(h16lo(hv.y), scv.z, shv.z), 0.f);
        float r3 = fmaxf(fmaf(h16hi(hv.y), scv.w, shv.w), 0.f);
        uint2 o;
        o.x = (unsigned)f2h(r0) | ((unsigned)f2h(r1) << 16);
        o.y = (unsigned)f2h(r2) | ((unsigned)f2h(r3) << 16);
        *(uint2*)&a16[(size_t)t * 4] = o;
    }
}

// ------- pull gather from pre-activated fp16: S16[n] = fp16(sum_e w_e*a16[src_e])
// One wave per node, 4 edge-streams x 16 channel-quads; uint2 row loads;
// 4 float4 acc chains -> ~16 outstanding row reads per wave. fp16 S output.
__global__ __launch_bounds__(256) void k_gather16(const int* __restrict__ rowptr,
                                                  const unsigned long long* __restrict__ edata,
                                                  const unsigned short* __restrict__ a16,
                                                  unsigned short* __restrict__ S16, int N) {
    int wid = (blockIdx.x * blockDim.x + threadIdx.x) >> 6;  // one wave per node
    if (wid >= N) return;
    int lane = threadIdx.x & 63;
    int s = lane >> 4;           // edge stream 0..3
    int q = lane & 15;           // channel quad (channels 4q..4q+3)
    unsigned c8 = (unsigned)(q << 3);  // byte offset of the quad in a 128B row

    int beg = rowptr[wid], end = rowptr[wid + 1];
    int len = end - beg;
    float4 acc[4];
#pragma unroll
    for (int j = 0; j < 4; ++j) { acc[j].x = 0.f; acc[j].y = 0.f; acc[j].z = 0.f; acc[j].w = 0.f; }
    int nFull = len & ~15;
    for (int base = 0; base < nFull; base += 16) {
#pragma unroll
        for (int j = 0; j < 4; ++j) {
            unsigned long long p = edata[beg + base + 4 * j + s];
            float w = __uint_as_float((unsigned)(p >> 32));
            unsigned off = (((unsigned)p) << 7) | c8;
            uint2 v = *(const uint2*)((const char*)a16 + off);
            acc[j].x = fmaf(w, h16lo(v.x), acc[j].x);
            acc[j].y = fmaf(w, h16hi(v.x), acc[j].y);
            acc[j].z = fmaf(w, h16lo(v.y), acc[j].z);
            acc[j].w = fmaf(w, h16hi(v.y), acc[j].w);
        }
    }
    if (nFull < len) {
#pragma unroll
        for (int j = 0; j < 4; ++j) {
            int idx = nFull + 4 * j + s;
            unsigned long long p = edata[beg + (idx < len ? idx : (len ? len - 1 : 0))];
            float w = (idx < len) ? __uint_as_float((unsigned)(p >> 32)) : 0.f;
            unsigned off = (((unsigned)p) << 7) | c8;
            uint2 v = *(const uint2*)((const char*)a16 + off);
            acc[j].x = fmaf(w, h16lo(v.x), acc[j].x);
            acc[j].y = fmaf(w, h16hi(v.x), acc[j].y);
            acc[j].z = fmaf(w, h16lo(v.y), acc[j].z);
            acc[j].w = fmaf(w, h16hi(v.y), acc[j].w);
        }
    }
    float4 r;
    r.x = (acc[0].x + acc[1].x) + (acc[2].x + acc[3].x);
    r.y = (acc[0].y + acc[1].y) + (acc[2].y + acc[3].y);
    r.z = (acc[0].z + acc[1].z) + (acc[2].z + acc[3].z);
    r.w = (acc[0].w + acc[1].w) + (acc[2].w + acc[3].w);
    r.x += __shfl_xor(r.x, 16); r.y += __shfl_xor(r.y, 16);
    r.z += __shfl_xor(r.z, 16); r.w += __shfl_xor(r.w, 16);
    r.x += __shfl_xor(r.x, 32); r.y += __shfl_xor(r.y, 32);
    r.z += __shfl_xor(r.z, 32); r.w += __shfl_xor(r.w, 32);
    if (s == 0) {
        uint2 o;
        o.x = (unsigned)f2h(r.x) | ((unsigned)f2h(r.y) << 16);
        o.y = (unsigned)f2h(r.z) | ((unsigned)f2h(r.w) << 16);
        *(uint2*)&S16[(size_t)wid * 64 + (q << 2)] = o;
    }
}

// ---- bf16x3 split helpers ----
__device__ __forceinline__ void split_pack8(const float* v, uint4& H, uint4& L) {
    unsigned hb[8], lb[8];
#pragma unroll
    for (int j = 0; j < 8; ++j) {
        unsigned b = __float_as_uint(v[j]);
        unsigned rb = (b + 0x7FFFu + ((b >> 16) & 1u)) & 0xFFFF0000u;  // RNE bf16
        hb[j] = rb >> 16;
        float lo = v[j] - __uint_as_float(rb);  // exact
        lb[j] = __float_as_uint(lo) >> 16;
    }
    H.x = hb[0] | (hb[1] << 16); H.y = hb[2] | (hb[3] << 16);
    H.z = hb[4] | (hb[5] << 16); H.w = hb[6] | (hb[7] << 16);
    L.x = lb[0] | (lb[1] << 16); L.y = lb[2] | (lb[3] << 16);
    L.z = lb[4] | (lb[5] << 16); L.w = lb[6] | (lb[7] << 16);
}

__device__ __forceinline__ void split_frag(const float* w, bf16x8& hi, bf16x8& lo) {
#pragma unroll
    for (int j = 0; j < 8; ++j) {
        unsigned b = __float_as_uint(w[j]);
        unsigned rb = (b + 0x7FFFu + ((b >> 16) & 1u)) & 0xFFFF0000u;
        hi[j] = (short)(rb >> 16);
        float lof = w[j] - __uint_as_float(rb);
        lo[j] = (short)(__float_as_uint(lof) >> 16);
    }
}

// --- h16_out = fp16(S@W1 + x@W3 - dw*(x@W2) + dw*b1 + b3) via bf16x3 MFMA.
// LDS staging: bijective XOR swizzle unit^=(unit>>4)&7 on 16B units, applied
// on BOTH write and read sides (conflict-free). PRE=1: S16/a16 fp16 inputs
// (exact hi/lo split). EMB=1: layer 0, S/x rows from g4/x via Wemb.
// BN stats accumulated from exact fp32 values.
template <int PRE, int EMB>
__global__ __launch_bounds__(512) void k_update(
    const unsigned short* __restrict__ S16, unsigned short* __restrict__ h16,
    const float* __restrict__ degw,
    const float* __restrict__ xin, const float* __restrict__ g4,
    const float* __restrict__ Wemb, const float* __restrict__ bemb,
    const unsigned short* __restrict__ a16,
    const float* __restrict__ W1, const float* __restrict__ b1,
    const float* __restrict__ W2, const float* __restrict__ W3,
    const float* __restrict__ b3,
    float* __restrict__ bnstats, int N) {
    // [Shi | Slo | Hhi | Hlo], 4096 ushorts (8KB) each = 32KB
    __shared__ __align__(16) unsigned short sA[16384];
    __shared__ float dwS[64];

    int tid = threadIdx.x;
    int lane = tid & 63;
    int wv = tid >> 6;            // wave 0..7
    int mg = wv >> 2;             // row-group: rows mg*32 .. mg*32+31
    int nb = wv & 3;              // col-block: cols nb*16 .. nb*16+15
    int c = (nb << 4) | (lane & 15);
    int krow = (lane >> 4) << 3;  // k-offset of this lane's fragment elems

    // ---- B fragments (weights) in registers, one-time ----
    bf16x8 B1h[2], B1l[2], B2h[2], B2l[2], B3h[2], B3l[2];
#pragma unroll
    for (int ks = 0; ks < 2; ++ks) {
        float w1v[8], w2v[8], w3v[8];
        int kb = ks * 32 + krow;
#pragma unroll
        for (int j = 0; j < 8; ++j) {
            int idx = (kb + j) * 64 + c;
            w1v[j] = W1[idx];
            w2v[j] = W2[idx];
            w3v[j] = W3[idx];
        }
        split_frag(w1v, B1h[ks], B1l[ks]);
        split_frag(w2v, B2h[ks], B2l[ks]);
        split_frag(w3v, B3h[ks], B3l[ks]);
    }
    float b1c = b1[c], b3c = b3[c];

    // ---- staging role: thread handles row r, k-chunk kg (8 consecutive k) ----
    int r = tid >> 3;   // 0..63
    int kg = tid & 7;   // 0..7
    int k0 = kg << 3;
    int unit0 = (((r >> 4) * 2 + (kg >> 2)) * 64) + ((kg & 3) << 4) + (r & 15);
    int slot = (unit0 ^ ((unit0 >> 4) & 7)) * 8;  // swizzled 16B-unit address

    float we0[8], we1[8], we2[8], we3[8], bev[8];
    if (EMB) {
#pragma unroll
        for (int j = 0; j < 8; ++j) {
            we0[j] = Wemb[k0 + j];
            we1[j] = Wemb[64 + k0 + j];
            we2[j] = Wemb[128 + k0 + j];
            we3[j] = Wemb[192 + k0 + j];
            bev[j] = bemb[k0 + j];
        }
    }

    float bsum = 0.f, bsq = 0.f;
    int numTiles = (N + 63) >> 6;
    for (int tile = blockIdx.x; tile < numTiles; tile += gridDim.x) {
        int n0 = tile << 6;
        __syncthreads();  // protect LDS from previous iteration's readers
        {
            int n = n0 + r;
            float sv[8], hv[8];
            if (n < N) {
                if (EMB) {
                    float4 g = *(const float4*)&g4[(size_t)n * 4];
                    float4 xr = *(const float4*)&xin[(size_t)n * 4];
                    float dw = degw[n];
#pragma unroll
                    for (int j = 0; j < 8; ++j) {
                        sv[j] = fmaf(g.x, we0[j], fmaf(g.y, we1[j],
                                 fmaf(g.z, we2[j], fmaf(g.w, we3[j], dw * bev[j]))));
                        hv[j] = fmaf(xr.x, we0[j], fmaf(xr.y, we1[j],
                                 fmaf(xr.z, we2[j], fmaf(xr.w, we3[j], bev[j]))));
                    }
                } else {
                    uint4 sp = *(const uint4*)&S16[(size_t)n * 64 + k0];
                    sv[0] = h16lo(sp.x); sv[1] = h16hi(sp.x);
                    sv[2] = h16lo(sp.y); sv[3] = h16hi(sp.y);
                    sv[4] = h16lo(sp.z); sv[5] = h16hi(sp.z);
                    sv[6] = h16lo(sp.w); sv[7] = h16hi(sp.w);
                    uint4 hp = *(const uint4*)((const char*)a16 + (((size_t)n) << 7) + (k0 << 1));
                    hv[0] = h16lo(hp.x); hv[1] = h16hi(hp.x);
                    hv[2] = h16lo(hp.y); hv[3] = h16hi(hp.y);
                    hv[4] = h16lo(hp.z); hv[5] = h16hi(hp.z);
                    hv[6] = h16lo(hp.w); hv[7] = h16hi(hp.w);
                }
            } else {
#pragma unroll
                for (int j = 0; j < 8; ++j) { sv[j] = 0.f; hv[j] = 0.f; }
            }
            uint4 H, L;
            split_pack8(sv, H, L);
            *(uint4*)&sA[slot] = H;
            *(uint4*)&sA[4096 + slot] = L;
            split_pack8(hv, H, L);
            *(uint4*)&sA[8192 + slot] = H;
            *(uint4*)&sA[12288 + slot] = L;
            if (tid < 64) dwS[tid] = (n0 + tid < N) ? degw[n0 + tid] : 0.f;
        }
        __syncthreads();
        // ---- MFMA: acc over K=64 (2 K-steps), 2 M-subtiles per wave ----
        f32x4 accP[2] = {{0.f,0.f,0.f,0.f},{0.f,0.f,0.f,0.f}};
        f32x4 accN[2] = {{0.f,0.f,0.f,0.f},{0.f,0.f,0.f,0.f}};
#pragma unroll
        for (int ks = 0; ks < 2; ++ks) {
#pragma unroll
            for (int mtg = 0; mtg < 2; ++mtg) {
                int mt = mg * 2 + mtg;
                int ub = (mt * 2 + ks) * 64 + lane;
                int base = (ub ^ ((ub >> 4) & 7)) * 8;  // swizzled read
                bf16x8 aSh = *(const bf16x8*)&sA[base];
                bf16x8 aSl = *(const bf16x8*)&sA[4096 + base];
                bf16x8 aHh = *(const bf16x8*)&sA[8192 + base];
                bf16x8 aHl = *(const bf16x8*)&sA[12288 + base];
                f32x4 p = accP[mtg], q = accN[mtg];
                p = __builtin_amdgcn_mfma_f32_16x16x32_bf16(aSh, B1h[ks], p, 0, 0, 0);
                p = __builtin_amdgcn_mfma_f32_16x16x32_bf16(aSl, B1h[ks], p, 0, 0, 0);
                p = __builtin_amdgcn_mfma_f32_16x16x32_bf16(aSh, B1l[ks], p, 0, 0, 0);
                p = __builtin_amdgcn_mfma_f32_16x16x32_bf16(aHh, B3h[ks], p, 0, 0, 0);
                p = __builtin_amdgcn_mfma_f32_16x16x32_bf16(aHl, B3h[ks], p, 0, 0, 0);
                p = __builtin_amdgcn_mfma_f32_16x16x32_bf16(aHh, B3l[ks], p, 0, 0, 0);
                q = __builtin_amdgcn_mfma_f32_16x16x32_bf16(aHh, B2h[ks], q, 0, 0, 0);
                q = __builtin_amdgcn_mfma_f32_16x16x32_bf16(aHl, B2h[ks], q, 0, 0, 0);
                q = __builtin_amdgcn_mfma_f32_16x16x32_bf16(aHh, B2l[ks], q, 0, 0, 0);
                accP[mtg] = p; accN[mtg] = q;
            }
        }
        // ---- epilogue: C layout col=lane&15, row=(lane>>4)*4+j ----
#pragma unroll
        for (int mtg = 0; mtg < 2; ++mtg) {
            int rowb = mg * 32 + mtg * 16 + ((lane >> 4) << 2);
            float4 dwv = *(const float4*)&dwS[rowb];
            float dwa[4] = {dwv.x, dwv.y, dwv.z, dwv.w};
#pragma unroll
            for (int j = 0; j < 4; ++j) {
                int n = n0 + rowb + j;
                if (n < N) {
                    float val = accP[mtg][j] - dwa[j] * accN[mtg][j] + dwa[j] * b1c + b3c;
                    h16[(size_t)n * 64 + c] = f2h(val);  // raw (pre-BN), fp16
                    bsum += val;
                    bsq += val * val;
                }
            }
        }
    }
    // ---- BN stats reduction (reuse sA as 1024 floats) ----
    __syncthreads();
    float* red = (float*)sA;
    red[tid] = bsum;
    red[512 + tid] = bsq;
    __syncthreads();
    if (tid < 64) {
        int nb_ = tid >> 4, cl = tid & 15;
        float s = 0.f, qq = 0.f;
#pragma unroll
        for (int i = 0; i < 8; ++i) {
            int t = ((i & 1) << 8) + (nb_ << 6) + ((i >> 1) << 4) + cl;
            s += red[t];
            qq += red[512 + t];
        }
        atomicAdd(&bnstats[tid], s);
        atomicAdd(&bnstats[64 + tid], qq);
    }
}

// ------- pool phase 1: per-graph sums of act(h16), sorted-run + atomics -------
#define POOL_TILE 128
__global__ __launch_bounds__(256) void k_poolsum(const unsigned short* __restrict__ h16,
                                                 const int* __restrict__ batch,
                                                 const float* __restrict__ bsp,
                                                 const float* __restrict__ gamp,
                                                 const float* __restrict__ betp,
                                                 float* __restrict__ gsums, int N) {
    int tid = threadIdx.x;
    int c = tid & 63, q = tid >> 6;
    float sc, sh_;
    bn_coeff(bsp, gamp, betp, c, 1.f / (float)N, sc, sh_);
    int n0 = blockIdx.x * POOL_TILE;
    int nEnd = n0 + POOL_TILE; if (nEnd > N) nEnd = N;
    int g = -1;
    float acc = 0.f;
    for (int n = n0 + q; n < nEnd; n += 4) {
        int b = batch[n];
        if (b != g) {
            if (g >= 0) atomicAdd(&gsums[(size_t)g * 64 + c], acc);
            g = b; acc = 0.f;
        }
        float hv = (float)__builtin_bit_cast(_Float16, h16[(size_t)n * 64 + c]);
        acc += fmaxf(fmaf(hv, sc, sh_), 0.f);
    }
    if (g >= 0) atomicAdd(&gsums[(size_t)g * 64 + c], acc);
}

// ------- pool phase 2: divide by count + MLP head (one 64-thread block / graph) -
__global__ void k_head(const float* __restrict__ gsums, const int* __restrict__ batch,
                       const float* __restrict__ Wl1, const float* __restrict__ bl1,
                       const float* __restrict__ Wl2, const float* __restrict__ bl2,
                       float* __restrict__ out, int N) {
    int g = blockIdx.x;
    int c = threadIdx.x;  // 64 threads
    int lo = 0, hi = N;
    while (lo < hi) { int mid = (lo + hi) >> 1; if (batch[mid] < g) lo = mid + 1; else hi = mid; }
    int start = lo;
    hi = N;
    while (lo < hi) { int mid = (lo + hi) >> 1; if (batch[mid] < g + 1) lo = mid + 1; else hi = mid; }
    int cnt = lo - start;
    float denom = (float)(cnt > 0 ? cnt : 1);
    __shared__ float gS[64], yS[64];
    gS[c] = gsums[(size_t)g * 64 + c] / denom;
    __syncthreads();
    float y = bl1[c];
    for (int k = 0; k < 64; ++k) y += gS[k] * Wl1[k * 64 + c];
    yS[c] = fmaxf(y, 0.f);
    __syncthreads();
    if (c < 3) {
        float o = bl2[c];
        for (int k = 0; k < 64; ++k) o += yS[k] * Wl2[k * 3 + c];
        out[g * 3 + c] = o;
    }
}

extern "C" void kernel_launch(void* const* d_in, const int* in_sizes, int n_in,
                              void* d_out, int out_size, void* d_ws, size_t ws_size,
                              hipStream_t stream) {
    const float* x     = (const float*)d_in[0];
    const int*   eid   = (const int*)d_in[1];
    const float* attr  = (const float*)d_in[2];
    const int*   batch = (const int*)d_in[3];
    const float* Wemb  = (const float*)d_in[4];
    const float* bemb  = (const float*)d_in[5];
    const float* W1    = (const float*)d_in[6];
    const float* b1    = (const float*)d_in[7];
    const float* W2    = (const float*)d_in[8];
    const float* W3    = (const float*)d_in[9];
    const float* b3    = (const float*)d_in[10];
    const float* gamma = (const float*)d_in[11];
    const float* beta  = (const float*)d_in[12];
    const float* Wl1   = (const float*)d_in[13];
    const float* bl1   = (const float*)d_in[14];
    const float* Wl2   = (const float*)d_in[15];
    const float* bl2   = (const float*)d_in[16];

    int N = in_sizes[3];
    int E = in_sizes[2];
    int L = in_sizes[7] / 64;
    int G = out_size / 3;

    const int* src = eid;
    const int* dst = eid + E;

    float* ws      = (float*)d_ws;
    float* h       = ws;                       // N*64 (fp16 used: N*64 ushorts)
    float* S       = h + (size_t)N * 64;       // N*64 (fp16 used)
    float* degw    = S + (size_t)N * 64;       // N
    float* g4      = degw + N;                 // N*4
    float* bnstats = g4 + (size_t)N * 4;       // 3*128 (per-layer slots)
    float* gsums   = bnstats + 3 * 128;        // G*64
    int*   gbase   = (int*)(gsums + (size_t)G * 64);  // NB+1
    int*   rowptr  = gbase + N;                // N+2
    int*   gcnt    = rowptr + (N + 2);         // 1024
    int*   gcur    = gcnt + 1024;              // 1024 (bucket cursors)
    unsigned long long* edata = (unsigned long long*)(gcur + 1024);  // E
    unsigned long long* tmp   = edata + E;                           // E
    unsigned short* a16 = (unsigned short*)(((uintptr_t)(tmp + E) + 15) & ~(uintptr_t)15);  // N*64 fp16
    unsigned short* h16 = (unsigned short*)h;   // N*64 fp16
    unsigned short* S16 = (unsigned short*)S;   // N*64 fp16

    int NB = (N + 255) >> 8;  // 256-node buckets (requires N < 2^24, NB <= 1024)

    // ---- CSR build + two-level counting sort of edges by dst (no per-edge
    // global atomics: LDS-aggregated bucket counts + per-bucket LDS histograms) --
    hipMemsetAsync(gcnt, 0, 1024 * sizeof(int), stream);
    hipMemsetAsync(bnstats, 0, 3 * 128 * sizeof(float), stream);
    k_countA<<<(E + ABLK - 1) / ABLK, 1024, 0, stream>>>(dst, gcnt, E, N);
    k_scanbuckets<<<1, 1024, 0, stream>>>(gcnt, gbase, gcur, rowptr, E, N);
    k_binA<<<(E + ABLK - 1) / ABLK, 1024, 0, stream>>>(src, dst, attr, gcur, tmp, E, N);
    k_binB3<<<NB, 256, 0, stream>>>(gbase, tmp, edata, rowptr, N);

    // ---- layers ----
    int gGrid = (N * 64 + 255) / 256;
    for (int l = 0; l < L; ++l) {
        if (l == 0) {
            // layer 0: 4-channel gather on raw x; S0/x0 reconstructed in update
            k_gather4<<<gGrid, 256, 0, stream>>>(rowptr, edata, x, g4, degw, N);
            k_update<0, 1><<<512, 512, 0, stream>>>(S16, h16, degw, x, g4, Wemb, bemb,
                                                    nullptr,
                                                    W1, b1, W2, W3, b3, bnstats, N);
        } else {
            k_gather16<<<gGrid, 256, 0, stream>>>(rowptr, edata, a16, S16, N);
            k_update<1, 0><<<512, 512, 0, stream>>>(S16, h16, degw, nullptr, nullptr,
                                                    nullptr, nullptr, a16,
                                                    W1 + (size_t)l * 4096, b1 + (size_t)l * 64,
                                                    W2 + (size_t)l * 4096, W3 + (size_t)l * 4096,
                                                    b3 + (size_t)l * 64,
                                                    bnstats + (size_t)l * 128, N);
        }
        if (l + 1 < L) {
            k_act<<<1024, 256, 0, stream>>>(h16, bnstats + (size_t)l * 128,
                                            gamma + (size_t)l * 64, beta + (size_t)l * 64,
                                            a16, N);
        }
    }

    // ---- pool (applies final BN affine + relu lazily) + head ----
    hipMemsetAsync(gsums, 0, (size_t)G * 64 * sizeof(float), stream);
    k_poolsum<<<(N + POOL_TILE - 1) / POOL_TILE, 256, 0, stream>>>(
        h16, batch, bnstats + (size_t)(L - 1) * 128, gamma + (size_t)(L - 1) * 64,
        beta + (size_t)(L - 1) * 64, gsums, N);
    k_head<<<G, 64, 0, stream>>>(gsums, batch, Wl1, bl1, Wl2, bl2, (float*)d_out, N);
}